// Round 2
// baseline (4847.727 us; speedup 1.0000x reference)
//
#include <hip/hip_runtime.h>
#include <stdint.h>

#define S_LEN 2048
#define B_SZ  64
#define I_SZ  512
#define H_SZ  512

typedef __attribute__((ext_vector_type(8))) short bf16x8;
typedef __attribute__((ext_vector_type(4))) float f32x4;

// f32 -> bf16 (RNE), no header dependency
__device__ __forceinline__ uint16_t f2b(float x) {
    uint32_t u = __float_as_uint(x);
    uint32_t r = (u + 0x7fffu + ((u >> 16) & 1u)) >> 16;
    return (uint16_t)r;
}

__device__ __forceinline__ float tfun(float v) {
    float e = __expf(2.f * v);
    return 1.f - 2.f / (e + 1.f);
}

// ---------------- kernel 1: convert weights to bf16 in ws ----------------
__global__ void cvt_weights_kernel(const float* __restrict__ wih,
                                   const float* __restrict__ whh,
                                   uint16_t* __restrict__ wihb,
                                   uint16_t* __restrict__ whhb) {
    int i = (blockIdx.x * blockDim.x + threadIdx.x) * 4;   // 256 blk * 256 thr * 4 = 262144
    float4 a = *reinterpret_cast<const float4*>(wih + i);
    float4 b = *reinterpret_cast<const float4*>(whh + i);
    union { uint16_t u[4]; uint2 v; } pa, pb;
    pa.u[0] = f2b(a.x); pa.u[1] = f2b(a.y); pa.u[2] = f2b(a.z); pa.u[3] = f2b(a.w);
    pb.u[0] = f2b(b.x); pb.u[1] = f2b(b.y); pb.u[2] = f2b(b.z); pb.u[3] = f2b(b.w);
    *reinterpret_cast<uint2*>(wihb + i) = pa.v;
    *reinterpret_cast<uint2*>(whhb + i) = pb.v;
}

// ---------------- kernel 2: x_proj GEMM  xp[sb,h] = input[sb,:] . Wih[h,:] + bias ---
#define BM 128
#define BN 128
#define BK 32

__launch_bounds__(256)
__global__ void xproj_gemm_kernel(const float* __restrict__ inp,      // [SB, I] f32
                                  const uint16_t* __restrict__ wihb,  // [H, I] bf16
                                  const float* __restrict__ bih,
                                  const float* __restrict__ bhh,
                                  float* __restrict__ xp)             // [SB, H] f32 (= d_out)
{
    __shared__ __align__(16) uint16_t Asm[2][BM * BK];
    __shared__ __align__(16) uint16_t Bsm[2][BN * BK];

    const int tid  = threadIdx.x;
    const int lane = tid & 63;
    const int w    = tid >> 6;            // 0..3
    const int wm   = (w >> 1) * 64;
    const int wn   = (w & 1) * 64;
    const int bid  = blockIdx.x;
    const int m0   = (bid >> 2) * BM;     // 1024 m-tiles
    const int n0   = (bid & 3) * BN;      // 4 n-tiles

    const int srow  = tid >> 1;           // 0..127
    const int shalf = (tid & 1) * 16;     // k offset 0/16

    float bsum[4];
#pragma unroll
    for (int nn = 0; nn < 4; ++nn) {
        int col = n0 + wn + nn * 16 + (lane & 15);
        bsum[nn] = bih[col] + bhh[col];
    }

    f32x4 acc[4][4];
#pragma unroll
    for (int mm = 0; mm < 4; ++mm)
#pragma unroll
        for (int nn = 0; nn < 4; ++nn)
            acc[mm][nn] = f32x4{0.f, 0.f, 0.f, 0.f};

    float4 ar[4];
    bf16x8 br[2];

    auto loadA = [&](int kt) {
        const float* g = inp + (size_t)(m0 + srow) * I_SZ + kt * BK + shalf;
#pragma unroll
        for (int q = 0; q < 4; ++q) ar[q] = *reinterpret_cast<const float4*>(g + q * 4);
    };
    auto loadB = [&](int kt) {
        const uint16_t* g = wihb + (size_t)(n0 + srow) * I_SZ + kt * BK + shalf;
        br[0] = *reinterpret_cast<const bf16x8*>(g);
        br[1] = *reinterpret_cast<const bf16x8*>(g + 8);
    };
    auto writeA = [&](int buf) {
        alignas(16) uint16_t tmp[16];
#pragma unroll
        for (int q = 0; q < 4; ++q) {
            tmp[q * 4 + 0] = f2b(ar[q].x); tmp[q * 4 + 1] = f2b(ar[q].y);
            tmp[q * 4 + 2] = f2b(ar[q].z); tmp[q * 4 + 3] = f2b(ar[q].w);
        }
        *reinterpret_cast<bf16x8*>(&Asm[buf][srow * BK + shalf])     = *reinterpret_cast<bf16x8*>(tmp);
        *reinterpret_cast<bf16x8*>(&Asm[buf][srow * BK + shalf + 8]) = *reinterpret_cast<bf16x8*>(tmp + 8);
    };
    auto writeB = [&](int buf) {
        *reinterpret_cast<bf16x8*>(&Bsm[buf][srow * BK + shalf])     = br[0];
        *reinterpret_cast<bf16x8*>(&Bsm[buf][srow * BK + shalf + 8]) = br[1];
    };

    loadA(0); loadB(0); writeA(0); writeB(0);
    __syncthreads();

    for (int kt = 0; kt < I_SZ / BK; ++kt) {
        const int cur = kt & 1;
        const bool more = (kt + 1) < I_SZ / BK;
        if (more) { loadA(kt + 1); loadB(kt + 1); }

        bf16x8 afrag[4], bfrag[4];
#pragma unroll
        for (int mm = 0; mm < 4; ++mm)
            afrag[mm] = *reinterpret_cast<const bf16x8*>(
                &Asm[cur][(wm + mm * 16 + (lane & 15)) * BK + (lane >> 4) * 8]);
#pragma unroll
        for (int nn = 0; nn < 4; ++nn)
            bfrag[nn] = *reinterpret_cast<const bf16x8*>(
                &Bsm[cur][(wn + nn * 16 + (lane & 15)) * BK + (lane >> 4) * 8]);
#pragma unroll
        for (int mm = 0; mm < 4; ++mm)
#pragma unroll
            for (int nn = 0; nn < 4; ++nn)
                acc[mm][nn] = __builtin_amdgcn_mfma_f32_16x16x32_bf16(
                    afrag[mm], bfrag[nn], acc[mm][nn], 0, 0, 0);

        if (more) { writeA(cur ^ 1); writeB(cur ^ 1); }
        __syncthreads();
    }

#pragma unroll
    for (int mm = 0; mm < 4; ++mm) {
        const int rbase = m0 + wm + mm * 16 + (lane >> 4) * 4;
#pragma unroll
        for (int nn = 0; nn < 4; ++nn) {
            const int col = n0 + wn + nn * 16 + (lane & 15);
#pragma unroll
            for (int r = 0; r < 4; ++r)
                xp[(size_t)(rbase + r) * H_SZ + col] = acc[mm][nn][r] + bsum[nn];
        }
    }
}

// ---------------- kernel 3: recurrence. One block per batch element. --------------
// h_new[j] = tanh(xp[s,b,j] + sum_k Whh[j,k] h[k]); xp lives in d_out, overwritten.
// 8 waves, wave w owns rows [w*64, w*64+64): 3 j-subtiles in VGPR, 1 in LDS.
// One barrier per step (lgkmcnt-only; global traffic is lane-private and floats
// across barriers). hsm double-buffered. Lanes r16<4 own accumulator jt=r16 and
// do the tanh epilogue (the 16 MFMA columns are redundant broadcast copies).

#define STEP(P, XP, sidx)                                                                   \
  {                                                                                          \
    f32x4 c0{0.f,0.f,0.f,0.f}, c1{0.f,0.f,0.f,0.f}, c2{0.f,0.f,0.f,0.f}, c3{0.f,0.f,0.f,0.f};\
    _Pragma("unroll")                                                                        \
    for (int kt = 0; kt < 16; ++kt) {                                                        \
      bf16x8 bf = *reinterpret_cast<const bf16x8*>(&hsm[P][kt * 32 + q * 8]);                \
      bf16x8 al = *reinterpret_cast<const bf16x8*>(&Asm[(w * 16 + kt) * 512 + lane * 8]);    \
      c0 = __builtin_amdgcn_mfma_f32_16x16x32_bf16(areg[kt],      bf, c0, 0, 0, 0);          \
      c1 = __builtin_amdgcn_mfma_f32_16x16x32_bf16(areg[16 + kt], bf, c1, 0, 0, 0);          \
      c2 = __builtin_amdgcn_mfma_f32_16x16x32_bf16(areg[32 + kt], bf, c2, 0, 0, 0);          \
      c3 = __builtin_amdgcn_mfma_f32_16x16x32_bf16(al,            bf, c3, 0, 0, 0);          \
    }                                                                                        \
    if (act) {                                                                               \
      f32x4 my = (c == 0) ? c0 : ((c == 1) ? c1 : ((c == 2) ? c2 : c3));                     \
      float t0 = tfun(my[0] + XP.x), t1 = tfun(my[1] + XP.y);                                \
      float t2 = tfun(my[2] + XP.z), t3 = tfun(my[3] + XP.w);                                \
      *reinterpret_cast<float4*>(out + ((size_t)(sidx) * B_SZ + b) * H_SZ + j0) =            \
          make_float4(t0, t1, t2, t3);                                                       \
      uint2 hp;                                                                              \
      hp.x = (uint32_t)f2b(t0) | ((uint32_t)f2b(t1) << 16);                                  \
      hp.y = (uint32_t)f2b(t2) | ((uint32_t)f2b(t3) << 16);                                  \
      *reinterpret_cast<uint2*>(&hsm[(P) ^ 1][j0]) = hp;                                     \
      int prow = ((sidx) + 2 <= S_LEN) ? ((sidx) + 2) : 0;                                   \
      XP = *reinterpret_cast<const float4*>(out + ((size_t)prow * B_SZ + b) * H_SZ + j0);    \
    }                                                                                        \
    asm volatile("s_waitcnt lgkmcnt(0)" ::: "memory");                                       \
    __builtin_amdgcn_s_barrier();                                                            \
  }

__launch_bounds__(512, 1)
__global__ void rnn_rec_kernel(const uint16_t* __restrict__ whhb,  // [H, H] bf16
                               const float* __restrict__ hx,       // [B, H] f32
                               float* __restrict__ out)            // [S*B*H | B*H] f32
{
    __shared__ __align__(16) uint16_t Asm[8 * 16 * 512];  // 128 KB: per-wave 4th j-subtile
    __shared__ __align__(16) uint16_t hsm[2][512];        // h in bf16, double-buffered

    const int tid  = threadIdx.x;   // 0..511
    const int lane = tid & 63;
    const int w    = tid >> 6;      // wave 0..7 -> rows [w*64, w*64+64)
    const int b    = blockIdx.x;    // batch
    const int r16  = lane & 15;
    const int q    = lane >> 4;     // 0..3

    // A fragments: rows j = w*64 + jt*16 + (lane&15), k = kt*32 + (lane>>4)*8 + e
    bf16x8 areg[48];
#pragma unroll
    for (int jt = 0; jt < 3; ++jt)
#pragma unroll
        for (int kt = 0; kt < 16; ++kt)
            areg[jt * 16 + kt] = *reinterpret_cast<const bf16x8*>(
                whhb + (size_t)(w * 64 + jt * 16 + r16) * H_SZ + kt * 32 + q * 8);
    // 4th j-subtile goes to LDS (re-read every step)
#pragma unroll
    for (int kt = 0; kt < 16; ++kt)
        *reinterpret_cast<bf16x8*>(&Asm[(w * 16 + kt) * 512 + lane * 8]) =
            *reinterpret_cast<const bf16x8*>(
                whhb + (size_t)(w * 64 + 48 + r16) * H_SZ + kt * 32 + q * 8);

    hsm[0][tid] = f2b(hx[(size_t)b * H_SZ + tid]);

    // Epilogue ownership: lanes with r16<4 own accumulator jt=r16,
    // rows j0..j0+3 where j0 = w*64 + r16*16 + q*4.
    const int  c   = r16;
    const bool act = (r16 < 4);
    const int  j0  = w * 64 + c * 16 + q * 4;

    float4 xpA = make_float4(0.f, 0.f, 0.f, 0.f);
    float4 xpB = make_float4(0.f, 0.f, 0.f, 0.f);
    if (act) {
        xpA = *reinterpret_cast<const float4*>(out + ((size_t)0 * B_SZ + b) * H_SZ + j0);
        xpB = *reinterpret_cast<const float4*>(out + ((size_t)1 * B_SZ + b) * H_SZ + j0);
    }
    __syncthreads();

    for (int s = 0; s < S_LEN; s += 2) {
        STEP(0, xpA, s);
        STEP(1, xpB, s + 1);
    }

    // h_last (bf16-rounded; well within threshold)
    uint32_t u = hsm[0][tid];
    out[(size_t)S_LEN * B_SZ * H_SZ + (size_t)b * H_SZ + tid] = __uint_as_float(u << 16);
}

// ---------------- launcher ----------------
extern "C" void kernel_launch(void* const* d_in, const int* in_sizes, int n_in,
                              void* d_out, int out_size, void* d_ws, size_t ws_size,
                              hipStream_t stream) {
    const float* inp = (const float*)d_in[0];
    const float* hx  = (const float*)d_in[1];
    const float* wih = (const float*)d_in[2];
    const float* whh = (const float*)d_in[3];
    const float* bih = (const float*)d_in[4];
    const float* bhh = (const float*)d_in[5];
    float* out = (float*)d_out;

    uint16_t* wihb = (uint16_t*)d_ws;
    uint16_t* whhb = wihb + (size_t)H_SZ * I_SZ;

    cvt_weights_kernel<<<256, 256, 0, stream>>>(wih, whh, wihb, whhb);

    const int grid_gemm = (S_LEN * B_SZ / BM) * (H_SZ / BN);  // 4096
    xproj_gemm_kernel<<<grid_gemm, 256, 0, stream>>>(inp, wihb, bih, bhh, out);

    rnn_rec_kernel<<<B_SZ, 512, 0, stream>>>(whhb, hx, out);
}

// Round 3
// 3096.081 us; speedup vs baseline: 1.5658x; 1.5658x over previous
//
#include <hip/hip_runtime.h>
#include <stdint.h>

#define S_LEN 2048
#define B_SZ  64
#define I_SZ  512
#define H_SZ  512

typedef __attribute__((ext_vector_type(8))) short bf16x8;
typedef __attribute__((ext_vector_type(4))) float f32x4;

// f32 -> bf16 (RNE), no header dependency
__device__ __forceinline__ uint16_t f2b(float x) {
    uint32_t u = __float_as_uint(x);
    uint32_t r = (u + 0x7fffu + ((u >> 16) & 1u)) >> 16;
    return (uint16_t)r;
}

__device__ __forceinline__ float tfun(float v) {
    float e = __expf(2.f * v);
    return 1.f - 2.f / (e + 1.f);
}

// ---------------- kernel 1: convert weights to bf16 in ws ----------------
__global__ void cvt_weights_kernel(const float* __restrict__ wih,
                                   const float* __restrict__ whh,
                                   uint16_t* __restrict__ wihb,
                                   uint16_t* __restrict__ whhb) {
    int i = (blockIdx.x * blockDim.x + threadIdx.x) * 4;
    float4 a = *reinterpret_cast<const float4*>(wih + i);
    float4 b = *reinterpret_cast<const float4*>(whh + i);
    union { uint16_t u[4]; uint2 v; } pa, pb;
    pa.u[0] = f2b(a.x); pa.u[1] = f2b(a.y); pa.u[2] = f2b(a.z); pa.u[3] = f2b(a.w);
    pb.u[0] = f2b(b.x); pb.u[1] = f2b(b.y); pb.u[2] = f2b(b.z); pb.u[3] = f2b(b.w);
    *reinterpret_cast<uint2*>(wihb + i) = pa.v;
    *reinterpret_cast<uint2*>(whhb + i) = pb.v;
}

// ---------------- kernel 2: x_proj GEMM  xp[sb,h] = input[sb,:] . Wih[h,:] + bias ---
#define BM 128
#define BN 128
#define BK 32

__launch_bounds__(256)
__global__ void xproj_gemm_kernel(const float* __restrict__ inp,      // [SB, I] f32
                                  const uint16_t* __restrict__ wihb,  // [H, I] bf16
                                  const float* __restrict__ bih,
                                  const float* __restrict__ bhh,
                                  float* __restrict__ xp)             // [SB, H] f32 (= d_out)
{
    __shared__ __align__(16) uint16_t Asm[2][BM * BK];
    __shared__ __align__(16) uint16_t Bsm[2][BN * BK];

    const int tid  = threadIdx.x;
    const int lane = tid & 63;
    const int w    = tid >> 6;
    const int wm   = (w >> 1) * 64;
    const int wn   = (w & 1) * 64;
    const int bid  = blockIdx.x;
    const int m0   = (bid >> 2) * BM;
    const int n0   = (bid & 3) * BN;

    const int srow  = tid >> 1;
    const int shalf = (tid & 1) * 16;

    float bsum[4];
#pragma unroll
    for (int nn = 0; nn < 4; ++nn) {
        int col = n0 + wn + nn * 16 + (lane & 15);
        bsum[nn] = bih[col] + bhh[col];
    }

    f32x4 acc[4][4];
#pragma unroll
    for (int mm = 0; mm < 4; ++mm)
#pragma unroll
        for (int nn = 0; nn < 4; ++nn)
            acc[mm][nn] = f32x4{0.f, 0.f, 0.f, 0.f};

    float4 ar[4];
    bf16x8 br[2];

    auto loadA = [&](int kt) {
        const float* g = inp + (size_t)(m0 + srow) * I_SZ + kt * BK + shalf;
#pragma unroll
        for (int q = 0; q < 4; ++q) ar[q] = *reinterpret_cast<const float4*>(g + q * 4);
    };
    auto loadB = [&](int kt) {
        const uint16_t* g = wihb + (size_t)(n0 + srow) * I_SZ + kt * BK + shalf;
        br[0] = *reinterpret_cast<const bf16x8*>(g);
        br[1] = *reinterpret_cast<const bf16x8*>(g + 8);
    };
    auto writeA = [&](int buf) {
        alignas(16) uint16_t tmp[16];
#pragma unroll
        for (int q = 0; q < 4; ++q) {
            tmp[q * 4 + 0] = f2b(ar[q].x); tmp[q * 4 + 1] = f2b(ar[q].y);
            tmp[q * 4 + 2] = f2b(ar[q].z); tmp[q * 4 + 3] = f2b(ar[q].w);
        }
        *reinterpret_cast<bf16x8*>(&Asm[buf][srow * BK + shalf])     = *reinterpret_cast<bf16x8*>(tmp);
        *reinterpret_cast<bf16x8*>(&Asm[buf][srow * BK + shalf + 8]) = *reinterpret_cast<bf16x8*>(tmp + 8);
    };
    auto writeB = [&](int buf) {
        *reinterpret_cast<bf16x8*>(&Bsm[buf][srow * BK + shalf])     = br[0];
        *reinterpret_cast<bf16x8*>(&Bsm[buf][srow * BK + shalf + 8]) = br[1];
    };

    loadA(0); loadB(0); writeA(0); writeB(0);
    __syncthreads();

    for (int kt = 0; kt < I_SZ / BK; ++kt) {
        const int cur = kt & 1;
        const bool more = (kt + 1) < I_SZ / BK;
        if (more) { loadA(kt + 1); loadB(kt + 1); }

        bf16x8 afrag[4], bfrag[4];
#pragma unroll
        for (int mm = 0; mm < 4; ++mm)
            afrag[mm] = *reinterpret_cast<const bf16x8*>(
                &Asm[cur][(wm + mm * 16 + (lane & 15)) * BK + (lane >> 4) * 8]);
#pragma unroll
        for (int nn = 0; nn < 4; ++nn)
            bfrag[nn] = *reinterpret_cast<const bf16x8*>(
                &Bsm[cur][(wn + nn * 16 + (lane & 15)) * BK + (lane >> 4) * 8]);
#pragma unroll
        for (int mm = 0; mm < 4; ++mm)
#pragma unroll
            for (int nn = 0; nn < 4; ++nn)
                acc[mm][nn] = __builtin_amdgcn_mfma_f32_16x16x32_bf16(
                    afrag[mm], bfrag[nn], acc[mm][nn], 0, 0, 0);

        if (more) { writeA(cur ^ 1); writeB(cur ^ 1); }
        __syncthreads();
    }

#pragma unroll
    for (int mm = 0; mm < 4; ++mm) {
        const int rbase = m0 + wm + mm * 16 + (lane >> 4) * 4;
#pragma unroll
        for (int nn = 0; nn < 4; ++nn) {
            const int col = n0 + wn + nn * 16 + (lane & 15);
#pragma unroll
            for (int r = 0; r < 4; ++r)
                xp[(size_t)(rbase + r) * H_SZ + col] = acc[mm][nn][r] + bsum[nn];
        }
    }
}

// ---------------- kernel 3: recurrence. One block per batch element. --------------
// h_new[j] = tanh(xp[s,b,j] + sum_k Whh[j,k] h[k]); xp lives in d_out, overwritten.
// 8 waves; wave w owns rows [w*64, w*64+64): j-subtiles 0..2 in 48 NAMED bf16x8
// registers (SROA-safe), subtile 3 in LDS. Two lgkm-only barriers per step; all
// global traffic is lane-private and floats across barriers (vmcnt never drained
// in the loop). hsm double-buffered; xp prefetched 2 steps ahead.

#define REP16(M) M(0) M(1) M(2) M(3) M(4) M(5) M(6) M(7) \
                 M(8) M(9) M(10) M(11) M(12) M(13) M(14) M(15)

#define LDW(jt, kt) (*reinterpret_cast<const bf16x8*>( \
    whhb + (size_t)(w * 64 + (jt) * 16 + r16) * H_SZ + (kt) * 32 + q * 8))

#define DECLA(k) bf16x8 rA##k, rB##k, rC##k;
#define LOADA(k) rA##k = LDW(0, k); rB##k = LDW(1, k); rC##k = LDW(2, k);

#define KSTEP(k) { \
    bf16x8 bf = *reinterpret_cast<const bf16x8*>(hb + (k) * 32 + q * 8); \
    bf16x8 al = *reinterpret_cast<const bf16x8*>(&Asm[(w * 16 + (k)) * 512 + lane * 8]); \
    c0 = __builtin_amdgcn_mfma_f32_16x16x32_bf16(rA##k, bf, c0, 0, 0, 0); \
    c1 = __builtin_amdgcn_mfma_f32_16x16x32_bf16(rB##k, bf, c1, 0, 0, 0); \
    c2 = __builtin_amdgcn_mfma_f32_16x16x32_bf16(rC##k, bf, c2, 0, 0, 0); \
    c3 = __builtin_amdgcn_mfma_f32_16x16x32_bf16(al,   bf, c3, 0, 0, 0); }

#define STEP(P, XP, sidx, CHKLAST)                                                          \
  {                                                                                          \
    const uint16_t* hb = &hsm[P][0];                                                         \
    f32x4 c0{0.f,0.f,0.f,0.f}, c1{0.f,0.f,0.f,0.f}, c2{0.f,0.f,0.f,0.f}, c3{0.f,0.f,0.f,0.f};\
    REP16(KSTEP)                                                                             \
    if (r16 == 0) {                                                                          \
      *reinterpret_cast<float4*>(&ysm[w * 64 +  0 + q * 4]) = make_float4(c0[0],c0[1],c0[2],c0[3]); \
      *reinterpret_cast<float4*>(&ysm[w * 64 + 16 + q * 4]) = make_float4(c1[0],c1[1],c1[2],c1[3]); \
      *reinterpret_cast<float4*>(&ysm[w * 64 + 32 + q * 4]) = make_float4(c2[0],c2[1],c2[2],c2[3]); \
      *reinterpret_cast<float4*>(&ysm[w * 64 + 48 + q * 4]) = make_float4(c3[0],c3[1],c3[2],c3[3]); \
    }                                                                                        \
    asm volatile("s_waitcnt lgkmcnt(0)" ::: "memory");                                       \
    __builtin_amdgcn_s_barrier();                                                            \
    float th = tfun(ysm[tid] + XP);                                                          \
    out[((size_t)(sidx) * B_SZ + b) * H_SZ + tid] = th;                                      \
    hsm[(P) ^ 1][tid] = f2b(th);                                                             \
    if (CHKLAST && (sidx) == S_LEN - 1)                                                      \
      out[(size_t)S_LEN * B_SZ * H_SZ + (size_t)b * H_SZ + tid] = th;                        \
    { int prow = ((sidx) + 2 < S_LEN) ? ((sidx) + 2) : 0;                                    \
      XP = out[((size_t)prow * B_SZ + b) * H_SZ + tid]; }                                    \
    asm volatile("s_waitcnt lgkmcnt(0)" ::: "memory");                                       \
    __builtin_amdgcn_s_barrier();                                                            \
  }

__launch_bounds__(512, 2)
__global__ void rnn_rec_kernel(const uint16_t* __restrict__ whhb,  // [H, H] bf16
                               const float* __restrict__ hx,       // [B, H] f32
                               float* __restrict__ out)            // [S*B*H | B*H] f32
{
    __shared__ __align__(16) uint16_t Asm[8 * 16 * 512];  // 128 KB: per-wave 4th j-subtile
    __shared__ __align__(16) uint16_t hsm[2][512];        // h in bf16, double-buffered
    __shared__ __align__(16) float    ysm[512];           // y = Whh @ h

    const int tid  = threadIdx.x;   // 0..511
    const int lane = tid & 63;
    const int w    = tid >> 6;      // wave 0..7 -> rows [w*64, w*64+64)
    const int b    = blockIdx.x;    // batch
    const int r16  = lane & 15;
    const int q    = lane >> 4;     // 0..3

    // A fragments in 48 named registers: rows j = w*64 + jt*16 + r16, k = kt*32 + q*8 + e
    REP16(DECLA)
    REP16(LOADA)

    // 4th j-subtile to LDS (re-read every step; 2-way-aliased b128 reads = free)
#pragma unroll
    for (int kt = 0; kt < 16; ++kt)
        *reinterpret_cast<bf16x8*>(&Asm[(w * 16 + kt) * 512 + lane * 8]) =
            *reinterpret_cast<const bf16x8*>(
                whhb + (size_t)(w * 64 + 48 + r16) * H_SZ + kt * 32 + q * 8);

    hsm[0][tid] = f2b(hx[(size_t)b * H_SZ + tid]);

    float xpA = out[((size_t)0 * B_SZ + b) * H_SZ + tid];
    float xpB = out[((size_t)1 * B_SZ + b) * H_SZ + tid];
    __syncthreads();

    for (int s = 0; s < S_LEN; s += 2) {
        STEP(0, xpA, s, 0)
        STEP(1, xpB, s + 1, 1)
    }
}

// ---------------- launcher ----------------
extern "C" void kernel_launch(void* const* d_in, const int* in_sizes, int n_in,
                              void* d_out, int out_size, void* d_ws, size_t ws_size,
                              hipStream_t stream) {
    const float* inp = (const float*)d_in[0];
    const float* hx  = (const float*)d_in[1];
    const float* wih = (const float*)d_in[2];
    const float* whh = (const float*)d_in[3];
    const float* bih = (const float*)d_in[4];
    const float* bhh = (const float*)d_in[5];
    float* out = (float*)d_out;

    uint16_t* wihb = (uint16_t*)d_ws;
    uint16_t* whhb = wihb + (size_t)H_SZ * I_SZ;

    cvt_weights_kernel<<<256, 256, 0, stream>>>(wih, whh, wihb, whhb);

    const int grid_gemm = (S_LEN * B_SZ / BM) * (H_SZ / BN);  // 4096
    xproj_gemm_kernel<<<grid_gemm, 256, 0, stream>>>(inp, wihb, bih, bhh, out);

    rnn_rec_kernel<<<B_SZ, 512, 0, stream>>>(whhb, hx, out);
}